// Round 5
// baseline (279.899 us; speedup 1.0000x reference)
//
#include <hip/hip_runtime.h>
#include <math.h>

#define EPS 1e-5f
#define N0 1000
#define NK1 500
#define NK2 100
#define NE 32000

__device__ __forceinline__ float bnr(float h, float sc, float sh) {
    float v = fmaf(h, sc, sh);
    return v > 0.f ? v : 0.f;
}

// ============================================================================
// K1: fused lin0+lin1. Each block redundantly computes FULL lin0 channel stats
// (192K FMA -> exact BN0), then its own 64-node lin1 tile with BN0+ReLU applied
// to recomputed h0 values. Writes h1 + per-block partial sums for BN1.
// ============================================================================
__global__ __launch_bounds__(256) void k_lin01(
        const float* __restrict__ x, const float* __restrict__ w0,
        const float* __restrict__ b0, const float* __restrict__ g0,
        const float* __restrict__ be0, const float* __restrict__ w1,
        const float* __restrict__ b1, float* __restrict__ h1,
        float* __restrict__ psum1) {
    __shared__ float xs[64][65], wsm[64][65];
    __shared__ float sc0[64], sh0[64];
    __shared__ float rs[256], rq[256];
    const int t = threadIdx.x, b = blockIdx.x;
    const int c = t & 63, ns = t >> 6;
    const int nb = b * 64;

    // full-graph lin0 stats (redundant per block)
    {
        float wa = w0[c * 3], wb = w0[c * 3 + 1], wc = w0[c * 3 + 2], bb = b0[c];
        float s = 0.f, q = 0.f;
        for (int n = ns; n < N0; n += 4) {
            float h = fmaf(wa, x[n * 3], fmaf(wb, x[n * 3 + 1], fmaf(wc, x[n * 3 + 2], bb)));
            s += h; q += h * h;
        }
        rs[t] = s; rq[t] = q;
        __syncthreads();
        if (ns == 0) {
            float S = rs[c] + rs[c + 64] + rs[c + 128] + rs[c + 192];
            float Q = rq[c] + rq[c + 64] + rq[c + 128] + rq[c + 192];
            float mu = S * (1.f / N0);
            float var = Q * (1.f / N0) - mu * mu;
            float sv = g0[c] * rsqrtf(var + EPS);
            sc0[c] = sv; sh0[c] = be0[c] - mu * sv;
        }
        __syncthreads();
    }

    // stage tile: recompute h0 rows, apply BN0+ReLU; stage w1
    for (int i = 0; i < 16; ++i) {
        int e = t + i * 256;
        int r = e >> 6, cc = e & 63;
        int n = nb + r;
        float v = 0.f;
        if (n < N0) {
            float h = fmaf(w0[cc * 3], x[n * 3],
                      fmaf(w0[cc * 3 + 1], x[n * 3 + 1],
                      fmaf(w0[cc * 3 + 2], x[n * 3 + 2], b0[cc])));
            v = bnr(h, sc0[cc], sh0[cc]);
        }
        xs[r][cc] = v;
        wsm[r][cc] = w1[e];
    }
    __syncthreads();

    float s = 0.f, q = 0.f;
    for (int j = 0; j < 16; ++j) {
        int ln = ns + 4 * j;
        int n = nb + ln;
        if (n < N0) {
            float acc = b1[c];
            #pragma unroll
            for (int k = 0; k < 64; ++k) acc = fmaf(xs[ln][k], wsm[c][k], acc);
            h1[n * 64 + c] = acc;
            s += acc; q += acc * acc;
        }
    }
    rs[t] = s; rq[t] = q;
    __syncthreads();
    if (ns == 0) {
        psum1[b * 128 + c]      = rs[c] + rs[c + 64] + rs[c + 128] + rs[c + 192];
        psum1[b * 128 + 64 + c] = rq[c] + rq[c + 64] + rq[c + 128] + rq[c + 192];
    }
}

// ============================================================================
// K2: fused pool1 + lin2a. 8 blocks x 1024 threads. Each block REDUNDANTLY
// runs the full pool1 (score1, LDS scatter, rank, select) entirely in LDS,
// then computes its own 63-node tile of lin2a directly from the gathered
// pooled features (xp1 never materialized). Also writes its 1/8 slice of the
// remapped edge list and per-block BN2a partial sums.
// ============================================================================
__global__ __launch_bounds__(1024) void k_pool1_lin2a(
        const float* __restrict__ h1, const float* __restrict__ psum1,
        const float* __restrict__ g1, const float* __restrict__ be1,
        const float* __restrict__ wrel, const float* __restrict__ wroot,
        const float* __restrict__ pb,
        const int* __restrict__ ei, const float* __restrict__ ea,
        const float* __restrict__ w2a, const float* __restrict__ b2a,
        float* __restrict__ h2a, float* __restrict__ psum2a,
        int* __restrict__ nsrc, int* __restrict__ ndst,
        float* __restrict__ new_ew) {
    union U {
        struct { float ss[N0], tt[N0], acc[N0]; int rk[N0]; } A;           // 16 KB
        struct { float xs[64][65], wsm[128][65], rs[1024], rq[1024]; } C;  // ~57 KB
    };
    __shared__ U u;
    __shared__ float bsc[64], bsh[64];
    __shared__ int pn[NK1];
    __shared__ float th[NK1];
    const int t = threadIdx.x, b = blockIdx.x;
    const int lane = t & 63, w = t >> 6;

    // BN1 coefficients from 16 partials
    if (t < 64) {
        float s = 0.f, q = 0.f;
        for (int i = 0; i < 16; ++i) { s += psum1[i * 128 + t]; q += psum1[i * 128 + 64 + t]; }
        float mu = s * (1.f / N0);
        float var = q * (1.f / N0) - mu * mu;
        float sv = g1[t] * rsqrtf(var + EPS);
        bsc[t] = sv; bsh[t] = be1[t] - mu * sv;
    }
    for (int i = t; i < N0; i += 1024) u.A.acc[i] = 0.f;
    __syncthreads();

    // score1: wave-per-node (coalesced h1 row reads)
    for (int n = w; n < N0; n += 16) {
        float v = bnr(h1[n * 64 + lane], bsc[lane], bsh[lane]);
        float dr = v * wrel[lane], dt = v * wroot[lane];
        #pragma unroll
        for (int m = 32; m >= 1; m >>= 1) {
            dr += __shfl_xor(dr, m, 64);
            dt += __shfl_xor(dt, m, 64);
        }
        if (lane == 0) { u.A.tt[n] = dr; u.A.ss[n] = dt + pb[0]; }
    }
    __syncthreads();

    // scatter (all edges, LDS accumulate)
    for (int e = t; e < NE; e += 1024) {
        float ew = ea[e];
        if (ew != 0.f) atomicAdd(&u.A.acc[ei[NE + e]], ew * u.A.tt[ei[e]]);
    }
    __syncthreads();
    for (int i = t; i < N0; i += 1024) u.A.ss[i] += u.A.acc[i];
    __syncthreads();

    // rank: thread-per-node, broadcast scan
    if (t < N0) {
        float s = u.A.ss[t];
        int r = 0;
        for (int m = 0; m < N0; ++m) {
            float smv = u.A.ss[m];
            r += (smv > s) || (smv == s && m < t);
        }
        u.A.rk[t] = r;
        if (r < NK1) { pn[r] = t; th[r] = tanhf(s); }
    }
    __syncthreads();

    // remap this block's 1/8 edge slice
    for (int e = b * 4000 + t; e < (b + 1) * 4000; e += 1024) {
        int s_ = ei[e], d_ = ei[NE + e];
        int rs_ = u.A.rk[s_], rd_ = u.A.rk[d_];
        bool v = (rs_ < NK1) && (rd_ < NK1);
        nsrc[e] = v ? rs_ : 0;
        ndst[e] = v ? rd_ : 0;
        new_ew[e] = v ? ea[e] : 0.f;
    }
    __syncthreads();  // union A dead after this point

    // lin2a tile: rows [b*63, b*63+nrows)
    const int nb = b * 63;
    const int nrows = (NK1 - nb) < 63 ? (NK1 - nb) : 63;
    for (int idx = t; idx < 64 * 64; idx += 1024) {
        int r = idx >> 6, c = idx & 63;
        float v = 0.f;
        if (r < nrows) {
            int n = pn[nb + r];
            v = bnr(h1[n * 64 + c], bsc[c], bsh[c]) * th[nb + r];
        }
        u.C.xs[r][c] = v;
    }
    for (int idx = t; idx < 128 * 64; idx += 1024) {
        int c = idx >> 6, k = idx & 63;
        u.C.wsm[c][k] = w2a[idx];
    }
    __syncthreads();

    const int c = t & 127, slot = t >> 7;
    float s = 0.f, q = 0.f;
    #pragma unroll
    for (int j = 0; j < 8; ++j) {
        int r = slot + 8 * j;
        if (r < nrows) {
            float acc = b2a[c];
            #pragma unroll
            for (int k = 0; k < 64; ++k) acc = fmaf(u.C.xs[r][k], u.C.wsm[c][k], acc);
            h2a[(nb + r) * 128 + c] = acc;
            s += acc; q += acc * acc;
        }
    }
    u.C.rs[t] = s; u.C.rq[t] = q;
    __syncthreads();
    if (slot == 0) {
        float S = 0.f, Q = 0.f;
        #pragma unroll
        for (int j = 0; j < 8; ++j) { S += u.C.rs[c + 128 * j]; Q += u.C.rq[c + 128 * j]; }
        psum2a[b * 256 + c]       = S;
        psum2a[b * 256 + 128 + c] = Q;
    }
}

// ============================================================================
// K3: lin2b (as R2), BN2a from 8 partials -> h2b + 20-block partial sums
// ============================================================================
__global__ __launch_bounds__(256) void k_lin2b(
        const float* __restrict__ h2a, const float* __restrict__ psum2a,
        const float* __restrict__ g2a, const float* __restrict__ be2a,
        const float* __restrict__ w2b, const float* __restrict__ b2b,
        float* __restrict__ h2b, float* __restrict__ psum2b) {
    __shared__ float wsm[200][33];
    __shared__ float xs[25][33];
    __shared__ float sc[128], sh[128];
    int t = threadIdx.x;
    if (t < 128) {
        float s = 0.f, q = 0.f;
        for (int i = 0; i < 8; ++i) { s += psum2a[i * 256 + t]; q += psum2a[i * 256 + 128 + t]; }
        float mu = s * (1.f / NK1);
        float var = q * (1.f / NK1) - mu * mu;
        float sv = g2a[t] * rsqrtf(var + EPS);
        sc[t] = sv; sh[t] = be2a[t] - mu * sv;
    }
    __syncthreads();
    int nb = blockIdx.x * 25;
    float acc[25];
    float bb = (t < 200) ? b2b[t] : 0.f;
    #pragma unroll
    for (int r = 0; r < 25; ++r) acc[r] = bb;
    for (int kt = 0; kt < 4; ++kt) {
        int k0 = kt * 32;
        __syncthreads();
        for (int e = t; e < 200 * 32; e += 256) {
            int r = e >> 5, k = e & 31;
            wsm[r][k] = w2b[r * 128 + k0 + k];
        }
        for (int e = t; e < 25 * 32; e += 256) {
            int r = e >> 5, k = e & 31;
            xs[r][k] = bnr(h2a[(nb + r) * 128 + k0 + k], sc[k0 + k], sh[k0 + k]);
        }
        __syncthreads();
        if (t < 200) {
            for (int k = 0; k < 32; ++k) {
                float wv = wsm[t][k];
                #pragma unroll
                for (int r = 0; r < 25; ++r) acc[r] = fmaf(xs[r][k], wv, acc[r]);
            }
        }
    }
    if (t < 200) {
        float s = 0.f, q = 0.f;
        #pragma unroll
        for (int r = 0; r < 25; ++r) {
            h2b[(nb + r) * 200 + t] = acc[r];
            s += acc[r]; q += acc[r] * acc[r];
        }
        psum2b[blockIdx.x * 400 + t]       = s;
        psum2b[blockIdx.x * 400 + 200 + t] = q;
    }
}

// ============================================================================
// K4: fused pool2 + global-max-pool + mlp_third + log_softmax. 1 block x 1024.
// xp2 never materialized; max-pool computed directly from selected rows.
// ============================================================================
__global__ __launch_bounds__(1024) void k_pool2_final(
        const float* __restrict__ h2b, const float* __restrict__ psum2b,
        const float* __restrict__ g2b, const float* __restrict__ be2b,
        const float* __restrict__ wrel, const float* __restrict__ wroot,
        const float* __restrict__ pb,
        const int* __restrict__ nsrc, const int* __restrict__ ndst,
        const float* __restrict__ new_ew,
        const float* __restrict__ w3a, const float* __restrict__ b3a,
        const float* __restrict__ w3b, const float* __restrict__ b3b,
        float* __restrict__ out) {
    __shared__ float bsc[200], bsh[200];
    __shared__ float ss[NK1], tt[NK1], acc[NK1];
    __shared__ int pn[NK2];
    __shared__ float th[NK2];
    __shared__ float gp[16 * 200];
    __shared__ float g[200], h3[128], o[2];
    const int t = threadIdx.x;
    const int lane = t & 63, w = t >> 6;

    if (t < 200) {
        float s = 0.f, q = 0.f;
        for (int i = 0; i < 20; ++i) { s += psum2b[i * 400 + t]; q += psum2b[i * 400 + 200 + t]; }
        float mu = s * (1.f / NK1);
        float var = q * (1.f / NK1) - mu * mu;
        float sv = g2b[t] * rsqrtf(var + EPS);
        bsc[t] = sv; bsh[t] = be2b[t] - mu * sv;
    }
    for (int i = t; i < NK1; i += 1024) acc[i] = 0.f;
    for (int i = t; i < 16 * 200; i += 1024) gp[i] = -1e30f;
    __syncthreads();

    // score2: wave-per-node
    for (int n = w; n < NK1; n += 16) {
        float dr = 0.f, dt = 0.f;
        #pragma unroll
        for (int j = 0; j < 4; ++j) {
            int ch = lane + 64 * j;
            if (ch < 200) {
                float v = bnr(h2b[n * 200 + ch], bsc[ch], bsh[ch]);
                dr = fmaf(v, wrel[ch], dr);
                dt = fmaf(v, wroot[ch], dt);
            }
        }
        #pragma unroll
        for (int m = 32; m >= 1; m >>= 1) {
            dr += __shfl_xor(dr, m, 64);
            dt += __shfl_xor(dt, m, 64);
        }
        if (lane == 0) { tt[n] = dr; ss[n] = dt + pb[0]; }
    }
    __syncthreads();

    // scatter2
    for (int e = t; e < NE; e += 1024) {
        float ew = new_ew[e];
        if (ew != 0.f) atomicAdd(&acc[ndst[e]], ew * tt[nsrc[e]]);
    }
    __syncthreads();
    for (int i = t; i < NK1; i += 1024) ss[i] += acc[i];
    __syncthreads();

    // rank2: thread-per-node broadcast scan
    if (t < NK1) {
        float s = ss[t];
        int r = 0;
        for (int m = 0; m < NK1; ++m) {
            float smv = ss[m];
            r += (smv > s) || (smv == s && m < t);
        }
        if (r < NK2) { pn[r] = t; th[r] = tanhf(s); }
    }
    __syncthreads();

    // global max pool over the 100 selected (scaled) rows, per-wave partials
    for (int j = w; j < NK2; j += 16) {
        int n = pn[j];
        float tn = th[j];
        #pragma unroll
        for (int jj = 0; jj < 4; ++jj) {
            int ch = lane + 64 * jj;
            if (ch < 200) {
                float v = bnr(h2b[n * 200 + ch], bsc[ch], bsh[ch]) * tn;
                gp[w * 200 + ch] = fmaxf(gp[w * 200 + ch], v);
            }
        }
    }
    __syncthreads();
    if (t < 200) {
        float m = gp[t];
        #pragma unroll
        for (int i = 1; i < 16; ++i) m = fmaxf(m, gp[i * 200 + t]);
        g[t] = m;
    }
    __syncthreads();

    // h3 = relu(w3a @ g + b3a): wave-per-output
    for (int r = w; r < 128; r += 16) {
        float p = 0.f;
        #pragma unroll
        for (int jj = 0; jj < 4; ++jj) {
            int ch = lane + 64 * jj;
            if (ch < 200) p = fmaf(w3a[r * 200 + ch], g[ch], p);
        }
        #pragma unroll
        for (int m = 32; m >= 1; m >>= 1) p += __shfl_xor(p, m, 64);
        if (lane == 0) h3[r] = fmaxf(p + b3a[r], 0.f);
    }
    __syncthreads();

    if (t < 128) {
        int ow = t >> 6;
        float p = w3b[ow * 128 + lane] * h3[lane]
                + w3b[ow * 128 + 64 + lane] * h3[64 + lane];
        #pragma unroll
        for (int m = 32; m >= 1; m >>= 1) p += __shfl_xor(p, m, 64);
        if (lane == 0) o[ow] = fmaxf(p + b3b[ow], 0.f);
    }
    __syncthreads();
    if (t == 0) {
        float m = fmaxf(o[0], o[1]);
        float l = m + logf(expf(o[0] - m) + expf(o[1] - m));
        out[0] = o[0] - l;
        out[1] = o[1] - l;
    }
}

extern "C" void kernel_launch(void* const* d_in, const int* in_sizes, int n_in,
                              void* d_out, int out_size, void* d_ws, size_t ws_size,
                              hipStream_t stream) {
    const float* x    = (const float*)d_in[0];
    const int*   ei   = (const int*)d_in[1];
    const float* ea   = (const float*)d_in[2];
    const float* w0   = (const float*)d_in[3];
    const float* b0   = (const float*)d_in[4];
    const float* g0   = (const float*)d_in[5];
    const float* be0  = (const float*)d_in[6];
    const float* w1   = (const float*)d_in[7];
    const float* b1   = (const float*)d_in[8];
    const float* g1   = (const float*)d_in[9];
    const float* be1  = (const float*)d_in[10];
    const float* w2a  = (const float*)d_in[11];
    const float* b2a  = (const float*)d_in[12];
    const float* g2a  = (const float*)d_in[13];
    const float* be2a = (const float*)d_in[14];
    const float* w2b  = (const float*)d_in[15];
    const float* b2b  = (const float*)d_in[16];
    const float* g2b  = (const float*)d_in[17];
    const float* be2b = (const float*)d_in[18];
    const float* w3a  = (const float*)d_in[19];
    const float* b3a  = (const float*)d_in[20];
    const float* w3b  = (const float*)d_in[21];
    const float* b3b  = (const float*)d_in[22];
    const float* p1_wrel  = (const float*)d_in[23];
    const float* p1_wroot = (const float*)d_in[24];
    const float* p1_b     = (const float*)d_in[25];
    const float* p2_wrel  = (const float*)d_in[26];
    const float* p2_wroot = (const float*)d_in[27];
    const float* p2_b     = (const float*)d_in[28];

    float* ws = (float*)d_ws;
    float* h1     = ws;                   // 64000
    float* psum1  = ws + 64000;           // 2048 (16 x 128)
    float* h2a    = ws + 66048;           // 64000
    float* psum2a = ws + 130048;          // 2048 (8 x 256)
    float* h2b    = ws + 132096;          // 100000
    float* psum2b = ws + 232096;          // 8000 (20 x 400)
    int*   nsrc   = (int*)(ws + 240096);  // 32000
    int*   ndst   = (int*)(ws + 272096);  // 32000
    float* new_ew = ws + 304096;          // 32000

    float* out = (float*)d_out;

    k_lin01<<<16, 256, 0, stream>>>(x, w0, b0, g0, be0, w1, b1, h1, psum1);
    k_pool1_lin2a<<<8, 1024, 0, stream>>>(h1, psum1, g1, be1,
                                          p1_wrel, p1_wroot, p1_b,
                                          ei, ea, w2a, b2a,
                                          h2a, psum2a, nsrc, ndst, new_ew);
    k_lin2b<<<20, 256, 0, stream>>>(h2a, psum2a, g2a, be2a, w2b, b2b, h2b, psum2b);
    k_pool2_final<<<1, 1024, 0, stream>>>(h2b, psum2b, g2b, be2b,
                                          p2_wrel, p2_wroot, p2_b,
                                          nsrc, ndst, new_ew,
                                          w3a, b3a, w3b, b3b, out);
}

// Round 6
// 150.931 us; speedup vs baseline: 1.8545x; 1.8545x over previous
//
#include <hip/hip_runtime.h>
#include <math.h>

#define EPS 1e-5f
#define N0 1000
#define NK1 500
#define NK2 100
#define NE 32000
#define NBLK 64

__device__ __forceinline__ float bnr(float h, float sc, float sh) {
    float v = fmaf(h, sc, sh);
    return v > 0.f ? v : 0.f;
}

// ---------------------------------------------------------------------------
// Grid barrier: single monotonic counter. Arrival: parallel __threadfence
// (release) + RELAXED fetch_add (cheap; no per-arrival L2 wb/inv).
// Spin: RELAXED loads (no buffer_inv per poll); ACQUIRE load every 16th poll
// guarantees eventual visibility; __threadfence on exit = acquire fence.
// ---------------------------------------------------------------------------
__device__ __forceinline__ void gsync(unsigned* bar, unsigned k) {
    __syncthreads();
    if (threadIdx.x == 0) {
        __threadfence();
        __hip_atomic_fetch_add(bar, 1u, __ATOMIC_RELAXED, __HIP_MEMORY_SCOPE_AGENT);
        const unsigned target = NBLK * k;
        unsigned spins = 0;
        while (true) {
            unsigned v;
            if ((++spins & 15u) == 0u)
                v = __hip_atomic_load(bar, __ATOMIC_ACQUIRE, __HIP_MEMORY_SCOPE_AGENT);
            else
                v = __hip_atomic_load(bar, __ATOMIC_RELAXED, __HIP_MEMORY_SCOPE_AGENT);
            if (v >= target) break;
            if (spins > (1u << 22)) break;  // hang safety (never triggers when resident)
            __builtin_amdgcn_s_sleep(1);
        }
        __threadfence();
    }
    __syncthreads();
}

struct Args {
    const float *x; const int *ei; const float *ea;
    const float *w0, *b0, *g0, *be0;
    const float *w1, *b1, *g1, *be1;
    const float *w2a, *b2a, *g2a, *be2a;
    const float *w2b, *b2b, *g2b, *be2b;
    const float *w3a, *b3a, *w3b, *b3b;
    const float *p1_wrel, *p1_wroot, *p1_b, *p2_wrel, *p2_wroot, *p2_b;
    float *h1, *psum1, *sc1, *t1, *xp1, *h2a, *psum2a;
    float *h2b, *psum2b, *t2, *sc2, *xp2;
    int *rk_g, *nsrc, *ndst; float *new_ew;
    unsigned *bar;
    float *out;
};

__global__ __launch_bounds__(256) void k_mega(Args a) {
    union __align__(16) SMem {
        struct { float xs[32][68], wsm[64][65], rs[256], rq[256], sc0[64], sh0[64]; } m1;
        struct { float xs[16][68], wsm[128][65], rs[256], rq[256]; } m2;
        struct { float wsm[200][33], xs[8][36], sc[128], sh[128]; } m3;
        struct { float acc[N0]; } sct;
        struct { float ss[N0], sc[200], sh[200]; } rk;
        struct { float sc[200], sh[200]; } bn;
        struct { float g[200], h3[128], o[2]; } fin;
    };
    __shared__ SMem sm;
    const int b = blockIdx.x, t = threadIdx.x;
    const int lane = t & 63, wv = t >> 6;

    // ======== P1: lin0+lin1 fused (32 blocks x 32-node tiles) ========
    if (b < 32) {
        const int c = lane, slot = wv;
        const int nb = b * 32;
        // redundant BN0 stats (pure VALU + broadcast loads; cheap)
        {
            float wa = a.w0[c * 3], wb = a.w0[c * 3 + 1], wc = a.w0[c * 3 + 2], bb = a.b0[c];
            float s = 0.f, q = 0.f;
            for (int n = slot; n < N0; n += 4) {
                float h = fmaf(wa, a.x[n * 3], fmaf(wb, a.x[n * 3 + 1], fmaf(wc, a.x[n * 3 + 2], bb)));
                s += h; q += h * h;
            }
            sm.m1.rs[t] = s; sm.m1.rq[t] = q;
            __syncthreads();
            if (t < 64) {
                float S = sm.m1.rs[t] + sm.m1.rs[t + 64] + sm.m1.rs[t + 128] + sm.m1.rs[t + 192];
                float Q = sm.m1.rq[t] + sm.m1.rq[t + 64] + sm.m1.rq[t + 128] + sm.m1.rq[t + 192];
                float mu = S * (1.f / N0);
                float var = Q * (1.f / N0) - mu * mu;
                float sv = a.g0[t] * rsqrtf(var + EPS);
                sm.m1.sc0[t] = sv; sm.m1.sh0[t] = a.be0[t] - mu * sv;
            }
            __syncthreads();
        }
        // stage tile (recompute h0 + BN0-relu) and w1
        for (int i = 0; i < 8; ++i) {
            int e = t + i * 256;
            int r = e >> 6, cc = e & 63;
            int n = nb + r;
            float v = 0.f;
            if (n < N0) {
                float h = fmaf(a.w0[cc * 3], a.x[n * 3],
                          fmaf(a.w0[cc * 3 + 1], a.x[n * 3 + 1],
                          fmaf(a.w0[cc * 3 + 2], a.x[n * 3 + 2], a.b0[cc])));
                v = bnr(h, sm.m1.sc0[cc], sm.m1.sh0[cc]);
            }
            sm.m1.xs[r][cc] = v;
        }
        for (int i = 0; i < 16; ++i) {
            int e = t + i * 256;
            sm.m1.wsm[e >> 6][e & 63] = a.w1[e];
        }
        __syncthreads();
        // inner: 4k x 4row register blocking
        float sacc = 0.f, qacc = 0.f;
        float bb1 = a.b1[c];
        for (int g = 0; g < 2; ++g) {
            int r0 = slot * 8 + g * 4;
            float a0 = bb1, a1 = bb1, a2 = bb1, a3 = bb1;
            #pragma unroll
            for (int kq = 0; kq < 16; ++kq) {
                float w0v = sm.m1.wsm[c][4 * kq], w1v = sm.m1.wsm[c][4 * kq + 1];
                float w2v = sm.m1.wsm[c][4 * kq + 2], w3v = sm.m1.wsm[c][4 * kq + 3];
                float4 x0 = *(const float4*)&sm.m1.xs[r0 + 0][4 * kq];
                float4 x1 = *(const float4*)&sm.m1.xs[r0 + 1][4 * kq];
                float4 x2 = *(const float4*)&sm.m1.xs[r0 + 2][4 * kq];
                float4 x3 = *(const float4*)&sm.m1.xs[r0 + 3][4 * kq];
                a0 = fmaf(x0.x, w0v, fmaf(x0.y, w1v, fmaf(x0.z, w2v, fmaf(x0.w, w3v, a0))));
                a1 = fmaf(x1.x, w0v, fmaf(x1.y, w1v, fmaf(x1.z, w2v, fmaf(x1.w, w3v, a1))));
                a2 = fmaf(x2.x, w0v, fmaf(x2.y, w1v, fmaf(x2.z, w2v, fmaf(x2.w, w3v, a2))));
                a3 = fmaf(x3.x, w0v, fmaf(x3.y, w1v, fmaf(x3.z, w2v, fmaf(x3.w, w3v, a3))));
            }
            float av[4] = {a0, a1, a2, a3};
            #pragma unroll
            for (int i = 0; i < 4; ++i) {
                int n = nb + r0 + i;
                if (n < N0) {
                    a.h1[n * 64 + c] = av[i];
                    sacc += av[i]; qacc += av[i] * av[i];
                }
            }
        }
        sm.m1.rs[t] = sacc; sm.m1.rq[t] = qacc;
        __syncthreads();
        if (t < 64) {
            a.psum1[b * 128 + t]      = sm.m1.rs[t] + sm.m1.rs[t + 64] + sm.m1.rs[t + 128] + sm.m1.rs[t + 192];
            a.psum1[b * 128 + 64 + t] = sm.m1.rq[t] + sm.m1.rq[t + 64] + sm.m1.rq[t + 128] + sm.m1.rq[t + 192];
        }
    }
    gsync(a.bar, 1);

    // ======== P2: score1 (63 blocks x 16 nodes, wave-per-node) ========
    if (b < 63) {
        if (t < 64) {
            float s = 0.f, q = 0.f;
            for (int i = 0; i < 32; ++i) { s += a.psum1[i * 128 + t]; q += a.psum1[i * 128 + 64 + t]; }
            float mu = s * (1.f / N0);
            float var = q * (1.f / N0) - mu * mu;
            float sv = a.g1[t] * rsqrtf(var + EPS);
            sm.bn.sc[t] = sv; sm.bn.sh[t] = a.be1[t] - mu * sv;
        }
        __syncthreads();
        for (int it = 0; it < 4; ++it) {
            int n = b * 16 + it * 4 + wv;
            if (n < N0) {
                float v = bnr(a.h1[n * 64 + lane], sm.bn.sc[lane], sm.bn.sh[lane]);
                float dr = v * a.p1_wrel[lane], dt = v * a.p1_wroot[lane];
                #pragma unroll
                for (int m = 32; m >= 1; m >>= 1) {
                    dr += __shfl_xor(dr, m, 64);
                    dt += __shfl_xor(dt, m, 64);
                }
                if (lane == 0) { a.t1[n] = dr; a.sc1[n] = dt + a.p1_b[0]; }
            }
        }
    }
    gsync(a.bar, 2);

    // ======== P3: scatter1 (16 blocks, LDS-aggregated) ========
    if (b < 16) {
        for (int i = t; i < N0; i += 256) sm.sct.acc[i] = 0.f;
        __syncthreads();
        for (int e = b * 256 + t; e < NE; e += 16 * 256) {
            float w = a.ea[e];
            if (w != 0.f) atomicAdd(&sm.sct.acc[a.ei[NE + e]], w * a.t1[a.ei[e]]);
        }
        __syncthreads();
        for (int i = t; i < N0; i += 256) {
            float v = sm.sct.acc[i];
            if (v != 0.f) atomicAdd(&a.sc1[i], v);
        }
    }
    gsync(a.bar, 3);

    // ======== P4: rank1 + select (63 blocks x 16 nodes) ========
    if (b < 63) {
        if (t < 64) {
            float s = 0.f, q = 0.f;
            for (int i = 0; i < 32; ++i) { s += a.psum1[i * 128 + t]; q += a.psum1[i * 128 + 64 + t]; }
            float mu = s * (1.f / N0);
            float var = q * (1.f / N0) - mu * mu;
            float sv = a.g1[t] * rsqrtf(var + EPS);
            sm.rk.sc[t] = sv; sm.rk.sh[t] = a.be1[t] - mu * sv;
        }
        for (int i = t; i < N0; i += 256) sm.rk.ss[i] = a.sc1[i];
        __syncthreads();
        for (int it = 0; it < 4; ++it) {
            int n = b * 16 + it * 4 + wv;
            if (n < N0) {
                float s = sm.rk.ss[n];
                int r = 0;
                for (int m = lane; m < N0; m += 64) {
                    float smv = sm.rk.ss[m];
                    r += (smv > s) || (smv == s && m < n);
                }
                #pragma unroll
                for (int msk = 32; msk >= 1; msk >>= 1) r += __shfl_xor(r, msk, 64);
                if (lane == 0) a.rk_g[n] = r;
                if (r < NK1) {
                    float tn = tanhf(s);
                    a.xp1[r * 64 + lane] = bnr(a.h1[n * 64 + lane], sm.rk.sc[lane], sm.rk.sh[lane]) * tn;
                }
            }
        }
    }
    gsync(a.bar, 4);

    // ======== P5: lin2a (32 blocks x 16 rows) + remap (32 blocks) ========
    if (b < 32) {
        const int nb = b * 16;
        const int nrows = (NK1 - nb) < 16 ? (NK1 - nb) : 16;
        for (int i = 0; i < 4; ++i) {
            int e = t + i * 256;
            int r = e >> 6, cc = e & 63;
            sm.m2.xs[r][cc] = (r < nrows) ? a.xp1[(nb + r) * 64 + cc] : 0.f;
        }
        for (int i = 0; i < 32; ++i) {
            int e = t + i * 256;
            sm.m2.wsm[e >> 6][e & 63] = a.w2a[e];
        }
        __syncthreads();
        const int c = t & 127, slot = t >> 7;
        float sacc = 0.f, qacc = 0.f;
        float bb2 = a.b2a[c];
        for (int g = 0; g < 2; ++g) {
            int r0 = slot * 8 + g * 4;
            float a0 = bb2, a1 = bb2, a2 = bb2, a3 = bb2;
            #pragma unroll
            for (int kq = 0; kq < 16; ++kq) {
                float w0v = sm.m2.wsm[c][4 * kq], w1v = sm.m2.wsm[c][4 * kq + 1];
                float w2v = sm.m2.wsm[c][4 * kq + 2], w3v = sm.m2.wsm[c][4 * kq + 3];
                float4 x0 = *(const float4*)&sm.m2.xs[r0 + 0][4 * kq];
                float4 x1 = *(const float4*)&sm.m2.xs[r0 + 1][4 * kq];
                float4 x2 = *(const float4*)&sm.m2.xs[r0 + 2][4 * kq];
                float4 x3 = *(const float4*)&sm.m2.xs[r0 + 3][4 * kq];
                a0 = fmaf(x0.x, w0v, fmaf(x0.y, w1v, fmaf(x0.z, w2v, fmaf(x0.w, w3v, a0))));
                a1 = fmaf(x1.x, w0v, fmaf(x1.y, w1v, fmaf(x1.z, w2v, fmaf(x1.w, w3v, a1))));
                a2 = fmaf(x2.x, w0v, fmaf(x2.y, w1v, fmaf(x2.z, w2v, fmaf(x2.w, w3v, a2))));
                a3 = fmaf(x3.x, w0v, fmaf(x3.y, w1v, fmaf(x3.z, w2v, fmaf(x3.w, w3v, a3))));
            }
            float av[4] = {a0, a1, a2, a3};
            #pragma unroll
            for (int i = 0; i < 4; ++i) {
                int r = r0 + i;
                if (r < nrows) {
                    a.h2a[(nb + r) * 128 + c] = av[i];
                    sacc += av[i]; qacc += av[i] * av[i];
                }
            }
        }
        sm.m2.rs[t] = sacc; sm.m2.rq[t] = qacc;
        __syncthreads();
        if (t < 128) {
            a.psum2a[b * 256 + t]       = sm.m2.rs[t] + sm.m2.rs[t + 128];
            a.psum2a[b * 256 + 128 + t] = sm.m2.rq[t] + sm.m2.rq[t + 128];
        }
    } else {
        int e0 = (b - 32) * 1000;
        for (int e = e0 + t; e < e0 + 1000; e += 256) {
            int s_ = a.ei[e], d_ = a.ei[NE + e];
            int rs_ = a.rk_g[s_], rd_ = a.rk_g[d_];
            bool v = (rs_ < NK1) && (rd_ < NK1);
            a.nsrc[e] = v ? rs_ : 0;
            a.ndst[e] = v ? rd_ : 0;
            a.new_ew[e] = v ? a.ea[e] : 0.f;
        }
    }
    gsync(a.bar, 5);

    // ======== P6: lin2b (64 blocks x 8 rows, k-tiled) ========
    {
        const int nb = b * 8;
        if (nb < NK1) {
            const int nrows = (NK1 - nb) < 8 ? (NK1 - nb) : 8;
            if (t < 128) {
                float s = 0.f, q = 0.f;
                for (int i = 0; i < 32; ++i) { s += a.psum2a[i * 256 + t]; q += a.psum2a[i * 256 + 128 + t]; }
                float mu = s * (1.f / NK1);
                float var = q * (1.f / NK1) - mu * mu;
                float sv = a.g2a[t] * rsqrtf(var + EPS);
                sm.m3.sc[t] = sv; sm.m3.sh[t] = a.be2a[t] - mu * sv;
            }
            float acc[8];
            float bb = (t < 200) ? a.b2b[t] : 0.f;
            #pragma unroll
            for (int r = 0; r < 8; ++r) acc[r] = bb;
            for (int kt = 0; kt < 4; ++kt) {
                int k0 = kt * 32;
                __syncthreads();
                for (int i = 0; i < 25; ++i) {
                    int e = t + i * 256;
                    int r = e >> 5, k = e & 31;
                    sm.m3.wsm[r][k] = a.w2b[r * 128 + k0 + k];
                }
                {
                    int r = t >> 5, k = t & 31;
                    sm.m3.xs[r][k] = (r < nrows)
                        ? bnr(a.h2a[(nb + r) * 128 + k0 + k], sm.m3.sc[k0 + k], sm.m3.sh[k0 + k]) : 0.f;
                }
                __syncthreads();
                if (t < 200) {
                    #pragma unroll
                    for (int kq = 0; kq < 8; ++kq) {
                        float w0v = sm.m3.wsm[t][4 * kq], w1v = sm.m3.wsm[t][4 * kq + 1];
                        float w2v = sm.m3.wsm[t][4 * kq + 2], w3v = sm.m3.wsm[t][4 * kq + 3];
                        #pragma unroll
                        for (int r = 0; r < 8; ++r) {
                            float4 xv = *(const float4*)&sm.m3.xs[r][4 * kq];
                            acc[r] = fmaf(xv.x, w0v, fmaf(xv.y, w1v, fmaf(xv.z, w2v, fmaf(xv.w, w3v, acc[r]))));
                        }
                    }
                }
            }
            if (t < 200) {
                float s = 0.f, q = 0.f;
                #pragma unroll
                for (int r = 0; r < 8; ++r) {
                    if (r < nrows) {
                        a.h2b[(nb + r) * 200 + t] = acc[r];
                        s += acc[r]; q += acc[r] * acc[r];
                    }
                }
                a.psum2b[b * 400 + t] = s;
                a.psum2b[b * 400 + 200 + t] = q;
            }
        } else if (t < 200) {
            a.psum2b[b * 400 + t] = 0.f;
            a.psum2b[b * 400 + 200 + t] = 0.f;
        }
    }
    gsync(a.bar, 6);

    // ======== P7: score2 (63 blocks x 8 nodes) ========
    if (b < 63) {
        if (t < 200) {
            float s = 0.f, q = 0.f;
            for (int i = 0; i < 64; ++i) { s += a.psum2b[i * 400 + t]; q += a.psum2b[i * 400 + 200 + t]; }
            float mu = s * (1.f / NK1);
            float var = q * (1.f / NK1) - mu * mu;
            float sv = a.g2b[t] * rsqrtf(var + EPS);
            sm.bn.sc[t] = sv; sm.bn.sh[t] = a.be2b[t] - mu * sv;
        }
        __syncthreads();
        for (int it = 0; it < 2; ++it) {
            int n = b * 8 + it * 4 + wv;
            if (n < NK1) {
                float dr = 0.f, dt = 0.f;
                #pragma unroll
                for (int j = 0; j < 4; ++j) {
                    int ch = lane + 64 * j;
                    if (ch < 200) {
                        float v = bnr(a.h2b[n * 200 + ch], sm.bn.sc[ch], sm.bn.sh[ch]);
                        dr = fmaf(v, a.p2_wrel[ch], dr);
                        dt = fmaf(v, a.p2_wroot[ch], dt);
                    }
                }
                #pragma unroll
                for (int m = 32; m >= 1; m >>= 1) {
                    dr += __shfl_xor(dr, m, 64);
                    dt += __shfl_xor(dt, m, 64);
                }
                if (lane == 0) { a.t2[n] = dr; a.sc2[n] = dt + a.p2_b[0]; }
            }
        }
    }
    gsync(a.bar, 7);

    // ======== P8: scatter2 (16 blocks) ========
    if (b < 16) {
        for (int i = t; i < NK1; i += 256) sm.sct.acc[i] = 0.f;
        __syncthreads();
        for (int e = b * 256 + t; e < NE; e += 16 * 256) {
            float w = a.new_ew[e];
            if (w != 0.f) atomicAdd(&sm.sct.acc[a.ndst[e]], w * a.t2[a.nsrc[e]]);
        }
        __syncthreads();
        for (int i = t; i < NK1; i += 256) {
            float v = sm.sct.acc[i];
            if (v != 0.f) atomicAdd(&a.sc2[i], v);
        }
    }
    gsync(a.bar, 8);

    // ======== P9: rank2 + select (63 blocks x 8 nodes) ========
    if (b < 63) {
        if (t < 200) {
            float s = 0.f, q = 0.f;
            for (int i = 0; i < 64; ++i) { s += a.psum2b[i * 400 + t]; q += a.psum2b[i * 400 + 200 + t]; }
            float mu = s * (1.f / NK1);
            float var = q * (1.f / NK1) - mu * mu;
            float sv = a.g2b[t] * rsqrtf(var + EPS);
            sm.rk.sc[t] = sv; sm.rk.sh[t] = a.be2b[t] - mu * sv;
        }
        for (int i = t; i < NK1; i += 256) sm.rk.ss[i] = a.sc2[i];
        __syncthreads();
        for (int it = 0; it < 2; ++it) {
            int n = b * 8 + it * 4 + wv;
            if (n < NK1) {
                float s = sm.rk.ss[n];
                int r = 0;
                for (int m = lane; m < NK1; m += 64) {
                    float smv = sm.rk.ss[m];
                    r += (smv > s) || (smv == s && m < n);
                }
                #pragma unroll
                for (int msk = 32; msk >= 1; msk >>= 1) r += __shfl_xor(r, msk, 64);
                if (r < NK2) {
                    float tn = tanhf(s);
                    #pragma unroll
                    for (int j = 0; j < 4; ++j) {
                        int ch = lane + 64 * j;
                        if (ch < 200)
                            a.xp2[r * 200 + ch] = bnr(a.h2b[n * 200 + ch], sm.rk.sc[ch], sm.rk.sh[ch]) * tn;
                    }
                }
            }
        }
    }
    gsync(a.bar, 9);

    // ======== P10: max-pool + mlp_third + log_softmax (block 0) ========
    if (b == 0) {
        if (t < 200) {
            float m = -1e30f;
            for (int n = 0; n < NK2; ++n) m = fmaxf(m, a.xp2[n * 200 + t]);
            sm.fin.g[t] = m;
        }
        __syncthreads();
        for (int r = wv; r < 128; r += 4) {
            float p = 0.f;
            #pragma unroll
            for (int j = 0; j < 4; ++j) {
                int ch = lane + 64 * j;
                if (ch < 200) p = fmaf(a.w3a[r * 200 + ch], sm.fin.g[ch], p);
            }
            #pragma unroll
            for (int m = 32; m >= 1; m >>= 1) p += __shfl_xor(p, m, 64);
            if (lane == 0) sm.fin.h3[r] = fmaxf(p + a.b3a[r], 0.f);
        }
        __syncthreads();
        if (t < 128) {
            int ow = t >> 6;
            float p = a.w3b[ow * 128 + lane] * sm.fin.h3[lane]
                    + a.w3b[ow * 128 + 64 + lane] * sm.fin.h3[64 + lane];
            #pragma unroll
            for (int m = 32; m >= 1; m >>= 1) p += __shfl_xor(p, m, 64);
            if (lane == 0) sm.fin.o[ow] = fmaxf(p + a.b3b[ow], 0.f);
        }
        __syncthreads();
        if (t == 0) {
            float m = fmaxf(sm.fin.o[0], sm.fin.o[1]);
            float l = m + logf(expf(sm.fin.o[0] - m) + expf(sm.fin.o[1] - m));
            a.out[0] = sm.fin.o[0] - l;
            a.out[1] = sm.fin.o[1] - l;
        }
    }
}

extern "C" void kernel_launch(void* const* d_in, const int* in_sizes, int n_in,
                              void* d_out, int out_size, void* d_ws, size_t ws_size,
                              hipStream_t stream) {
    float* ws = (float*)d_ws;

    Args a;
    a.x    = (const float*)d_in[0];
    a.ei   = (const int*)d_in[1];
    a.ea   = (const float*)d_in[2];
    a.w0   = (const float*)d_in[3];  a.b0   = (const float*)d_in[4];
    a.g0   = (const float*)d_in[5];  a.be0  = (const float*)d_in[6];
    a.w1   = (const float*)d_in[7];  a.b1   = (const float*)d_in[8];
    a.g1   = (const float*)d_in[9];  a.be1  = (const float*)d_in[10];
    a.w2a  = (const float*)d_in[11]; a.b2a  = (const float*)d_in[12];
    a.g2a  = (const float*)d_in[13]; a.be2a = (const float*)d_in[14];
    a.w2b  = (const float*)d_in[15]; a.b2b  = (const float*)d_in[16];
    a.g2b  = (const float*)d_in[17]; a.be2b = (const float*)d_in[18];
    a.w3a  = (const float*)d_in[19]; a.b3a  = (const float*)d_in[20];
    a.w3b  = (const float*)d_in[21]; a.b3b  = (const float*)d_in[22];
    a.p1_wrel  = (const float*)d_in[23];
    a.p1_wroot = (const float*)d_in[24];
    a.p1_b     = (const float*)d_in[25];
    a.p2_wrel  = (const float*)d_in[26];
    a.p2_wroot = (const float*)d_in[27];
    a.p2_b     = (const float*)d_in[28];

    a.h1     = ws;                      // 64000
    a.psum1  = ws + 64000;              // 4096  (32 x 128)
    a.rk_g   = (int*)(ws + 68096);      // 1000
    a.sc1    = ws + 69096;              // 1000
    a.t1     = ws + 70096;              // 1000
    a.xp1    = ws + 71096;              // 32000
    a.h2a    = ws + 103096;             // 64000
    a.psum2a = ws + 167096;             // 8192  (32 x 256)
    a.h2b    = ws + 175288;             // 100000
    a.psum2b = ws + 275288;             // 25600 (64 x 400)
    a.t2     = ws + 300888;             // 500
    a.sc2    = ws + 301388;             // 500
    a.xp2    = ws + 301888;             // 20000
    a.nsrc   = (int*)(ws + 321888);     // 32000
    a.ndst   = (int*)(ws + 353888);     // 32000
    a.new_ew = ws + 385888;             // 32000
    a.bar    = (unsigned*)(ws + 417888);
    a.out    = (float*)d_out;

    hipMemsetAsync((void*)a.bar, 0, sizeof(unsigned), stream);
    k_mega<<<NBLK, 256, 0, stream>>>(a);
}

// Round 7
// 126.959 us; speedup vs baseline: 2.2046x; 1.1888x over previous
//
#include <hip/hip_runtime.h>
#include <math.h>

#define EPS 1e-5f
#define N0 1000
#define NK1 500
#define NK2 100
#define NE 32000
#define NBLK 64

__device__ __forceinline__ float bnr(float h, float sc, float sh) {
    float v = fmaf(h, sc, sh);
    return v > 0.f ? v : 0.f;
}

// All cross-block workspace traffic goes through RELAXED agent-scope atomics:
// these compile to global ops that bypass the non-coherent L1/L2 and hit the
// coherence point, so no buffer_wbl2/buffer_inv fences are ever required.
__device__ __forceinline__ float aload(const float* p) {
    return __hip_atomic_load(p, __ATOMIC_RELAXED, __HIP_MEMORY_SCOPE_AGENT);
}
__device__ __forceinline__ void astore(float* p, float v) {
    __hip_atomic_store(p, v, __ATOMIC_RELAXED, __HIP_MEMORY_SCOPE_AGENT);
}
__device__ __forceinline__ int aiload(const int* p) {
    return __hip_atomic_load(p, __ATOMIC_RELAXED, __HIP_MEMORY_SCOPE_AGENT);
}
__device__ __forceinline__ void aistore(int* p, int v) {
    __hip_atomic_store(p, v, __ATOMIC_RELAXED, __HIP_MEMORY_SCOPE_AGENT);
}

// Fence-free grid barrier. Every wave drains its outstanding vmem (so all this
// block's atomic data stores have completed at the coherence point), then one
// lane bumps the counter and spins with RELAXED loads (each load reads the
// coherence point directly; no invalidates needed).
__device__ __forceinline__ void gsync(unsigned* bar, unsigned k) {
    asm volatile("s_waitcnt vmcnt(0) lgkmcnt(0)" ::: "memory");
    __syncthreads();
    if (threadIdx.x == 0) {
        __hip_atomic_fetch_add(bar, 1u, __ATOMIC_RELAXED, __HIP_MEMORY_SCOPE_AGENT);
        const unsigned target = NBLK * k;
        unsigned spins = 0;
        while (__hip_atomic_load(bar, __ATOMIC_RELAXED, __HIP_MEMORY_SCOPE_AGENT) < target) {
            if (++spins > (1u << 20)) break;  // hang safety
            __builtin_amdgcn_s_sleep(1);
        }
    }
    __syncthreads();
}

struct Args {
    const float *x; const int *ei; const float *ea;
    const float *w0, *b0, *g0, *be0;
    const float *w1, *b1, *g1, *be1;
    const float *w2a, *b2a, *g2a, *be2a;
    const float *w2b, *b2b, *g2b, *be2b;
    const float *w3a, *b3a, *w3b, *b3b;
    const float *p1_wrel, *p1_wroot, *p1_b, *p2_wrel, *p2_wroot, *p2_b;
    float *h1, *psum1, *sc1, *t1, *xp1, *h2a, *psum2a;
    float *h2b, *psum2b, *t2, *sc2, *xp2;
    int *rk_g, *nsrc, *ndst; float *new_ew;
    unsigned *bar;
    float *out;
};

__global__ __launch_bounds__(256) void k_mega(Args a) {
    union __align__(16) SMem {
        struct { float xs[32][68], wsm[64][65], rs[256], rq[256], sc0[64], sh0[64]; } m1;
        struct { float xs[16][68], wsm[128][65], rs[256], rq[256]; } m2;
        struct { float wsm[200][33], xs[8][36], sc[128], sh[128]; } m3;
        struct { float acc[N0]; } sct;
        struct { float ss[N0], sc[200], sh[200]; } rk;
        struct { float sc[200], sh[200]; } bn;
        struct { float g[200], h3[128], o[2]; } fin;
    };
    __shared__ SMem sm;
    const int b = blockIdx.x, t = threadIdx.x;
    const int lane = t & 63, wv = t >> 6;

    // ======== P1: lin0+lin1 fused (32 blocks x 32-node tiles) ========
    if (b < 32) {
        const int c = lane, slot = wv;
        const int nb = b * 32;
        {
            float wa = a.w0[c * 3], wb = a.w0[c * 3 + 1], wc = a.w0[c * 3 + 2], bb = a.b0[c];
            float s = 0.f, q = 0.f;
            for (int n = slot; n < N0; n += 4) {
                float h = fmaf(wa, a.x[n * 3], fmaf(wb, a.x[n * 3 + 1], fmaf(wc, a.x[n * 3 + 2], bb)));
                s += h; q += h * h;
            }
            sm.m1.rs[t] = s; sm.m1.rq[t] = q;
            __syncthreads();
            if (t < 64) {
                float S = sm.m1.rs[t] + sm.m1.rs[t + 64] + sm.m1.rs[t + 128] + sm.m1.rs[t + 192];
                float Q = sm.m1.rq[t] + sm.m1.rq[t + 64] + sm.m1.rq[t + 128] + sm.m1.rq[t + 192];
                float mu = S * (1.f / N0);
                float var = Q * (1.f / N0) - mu * mu;
                float sv = a.g0[t] * rsqrtf(var + EPS);
                sm.m1.sc0[t] = sv; sm.m1.sh0[t] = a.be0[t] - mu * sv;
            }
            __syncthreads();
        }
        for (int i = 0; i < 8; ++i) {
            int e = t + i * 256;
            int r = e >> 6, cc = e & 63;
            int n = nb + r;
            float v = 0.f;
            if (n < N0) {
                float h = fmaf(a.w0[cc * 3], a.x[n * 3],
                          fmaf(a.w0[cc * 3 + 1], a.x[n * 3 + 1],
                          fmaf(a.w0[cc * 3 + 2], a.x[n * 3 + 2], a.b0[cc])));
                v = bnr(h, sm.m1.sc0[cc], sm.m1.sh0[cc]);
            }
            sm.m1.xs[r][cc] = v;
        }
        for (int i = 0; i < 16; ++i) {
            int e = t + i * 256;
            sm.m1.wsm[e >> 6][e & 63] = a.w1[e];
        }
        __syncthreads();
        float sacc = 0.f, qacc = 0.f;
        float bb1 = a.b1[c];
        for (int g = 0; g < 2; ++g) {
            int r0 = slot * 8 + g * 4;
            float a0 = bb1, a1 = bb1, a2 = bb1, a3 = bb1;
            #pragma unroll
            for (int kq = 0; kq < 16; ++kq) {
                float w0v = sm.m1.wsm[c][4 * kq], w1v = sm.m1.wsm[c][4 * kq + 1];
                float w2v = sm.m1.wsm[c][4 * kq + 2], w3v = sm.m1.wsm[c][4 * kq + 3];
                float4 x0 = *(const float4*)&sm.m1.xs[r0 + 0][4 * kq];
                float4 x1 = *(const float4*)&sm.m1.xs[r0 + 1][4 * kq];
                float4 x2 = *(const float4*)&sm.m1.xs[r0 + 2][4 * kq];
                float4 x3 = *(const float4*)&sm.m1.xs[r0 + 3][4 * kq];
                a0 = fmaf(x0.x, w0v, fmaf(x0.y, w1v, fmaf(x0.z, w2v, fmaf(x0.w, w3v, a0))));
                a1 = fmaf(x1.x, w0v, fmaf(x1.y, w1v, fmaf(x1.z, w2v, fmaf(x1.w, w3v, a1))));
                a2 = fmaf(x2.x, w0v, fmaf(x2.y, w1v, fmaf(x2.z, w2v, fmaf(x2.w, w3v, a2))));
                a3 = fmaf(x3.x, w0v, fmaf(x3.y, w1v, fmaf(x3.z, w2v, fmaf(x3.w, w3v, a3))));
            }
            float av[4] = {a0, a1, a2, a3};
            #pragma unroll
            for (int i = 0; i < 4; ++i) {
                int n = nb + r0 + i;
                if (n < N0) {
                    astore(&a.h1[n * 64 + c], av[i]);
                    sacc += av[i]; qacc += av[i] * av[i];
                }
            }
        }
        sm.m1.rs[t] = sacc; sm.m1.rq[t] = qacc;
        __syncthreads();
        if (t < 64) {
            astore(&a.psum1[b * 128 + t],      sm.m1.rs[t] + sm.m1.rs[t + 64] + sm.m1.rs[t + 128] + sm.m1.rs[t + 192]);
            astore(&a.psum1[b * 128 + 64 + t], sm.m1.rq[t] + sm.m1.rq[t + 64] + sm.m1.rq[t + 128] + sm.m1.rq[t + 192]);
        }
    }
    gsync(a.bar, 1);

    // ======== P2: score1 (63 blocks x 16 nodes, wave-per-node) ========
    if (b < 63) {
        if (t < 64) {
            float s = 0.f, q = 0.f;
            for (int i = 0; i < 32; ++i) { s += aload(&a.psum1[i * 128 + t]); q += aload(&a.psum1[i * 128 + 64 + t]); }
            float mu = s * (1.f / N0);
            float var = q * (1.f / N0) - mu * mu;
            float sv = a.g1[t] * rsqrtf(var + EPS);
            sm.bn.sc[t] = sv; sm.bn.sh[t] = a.be1[t] - mu * sv;
        }
        __syncthreads();
        for (int it = 0; it < 4; ++it) {
            int n = b * 16 + it * 4 + wv;
            if (n < N0) {
                float v = bnr(aload(&a.h1[n * 64 + lane]), sm.bn.sc[lane], sm.bn.sh[lane]);
                float dr = v * a.p1_wrel[lane], dt = v * a.p1_wroot[lane];
                #pragma unroll
                for (int m = 32; m >= 1; m >>= 1) {
                    dr += __shfl_xor(dr, m, 64);
                    dt += __shfl_xor(dt, m, 64);
                }
                if (lane == 0) { astore(&a.t1[n], dr); astore(&a.sc1[n], dt + a.p1_b[0]); }
            }
        }
    }
    gsync(a.bar, 2);

    // ======== P3: scatter1 (16 blocks, LDS-aggregated) ========
    if (b < 16) {
        for (int i = t; i < N0; i += 256) sm.sct.acc[i] = 0.f;
        __syncthreads();
        for (int e = b * 256 + t; e < NE; e += 16 * 256) {
            float w = a.ea[e];
            if (w != 0.f) atomicAdd(&sm.sct.acc[a.ei[NE + e]], w * aload(&a.t1[a.ei[e]]));
        }
        __syncthreads();
        for (int i = t; i < N0; i += 256) {
            float v = sm.sct.acc[i];
            if (v != 0.f) atomicAdd(&a.sc1[i], v);
        }
    }
    gsync(a.bar, 3);

    // ======== P4: rank1 + select (63 blocks x 16 nodes) ========
    if (b < 63) {
        if (t < 64) {
            float s = 0.f, q = 0.f;
            for (int i = 0; i < 32; ++i) { s += aload(&a.psum1[i * 128 + t]); q += aload(&a.psum1[i * 128 + 64 + t]); }
            float mu = s * (1.f / N0);
            float var = q * (1.f / N0) - mu * mu;
            float sv = a.g1[t] * rsqrtf(var + EPS);
            sm.rk.sc[t] = sv; sm.rk.sh[t] = a.be1[t] - mu * sv;
        }
        for (int i = t; i < N0; i += 256) sm.rk.ss[i] = aload(&a.sc1[i]);
        __syncthreads();
        for (int it = 0; it < 4; ++it) {
            int n = b * 16 + it * 4 + wv;
            if (n < N0) {
                float s = sm.rk.ss[n];
                int r = 0;
                for (int m = lane; m < N0; m += 64) {
                    float smv = sm.rk.ss[m];
                    r += (smv > s) || (smv == s && m < n);
                }
                #pragma unroll
                for (int msk = 32; msk >= 1; msk >>= 1) r += __shfl_xor(r, msk, 64);
                if (lane == 0) aistore(&a.rk_g[n], r);
                if (r < NK1) {
                    float tn = tanhf(s);
                    astore(&a.xp1[r * 64 + lane],
                           bnr(aload(&a.h1[n * 64 + lane]), sm.rk.sc[lane], sm.rk.sh[lane]) * tn);
                }
            }
        }
    }
    gsync(a.bar, 4);

    // ======== P5: lin2a (32 blocks x 16 rows) + remap (32 blocks) ========
    if (b < 32) {
        const int nb = b * 16;
        const int nrows = (NK1 - nb) < 16 ? (NK1 - nb) : 16;
        for (int i = 0; i < 4; ++i) {
            int e = t + i * 256;
            int r = e >> 6, cc = e & 63;
            sm.m2.xs[r][cc] = (r < nrows) ? aload(&a.xp1[(nb + r) * 64 + cc]) : 0.f;
        }
        for (int i = 0; i < 32; ++i) {
            int e = t + i * 256;
            sm.m2.wsm[e >> 6][e & 63] = a.w2a[e];
        }
        __syncthreads();
        const int c = t & 127, slot = t >> 7;
        float sacc = 0.f, qacc = 0.f;
        float bb2 = a.b2a[c];
        for (int g = 0; g < 2; ++g) {
            int r0 = slot * 8 + g * 4;
            float a0 = bb2, a1 = bb2, a2 = bb2, a3 = bb2;
            #pragma unroll
            for (int kq = 0; kq < 16; ++kq) {
                float w0v = sm.m2.wsm[c][4 * kq], w1v = sm.m2.wsm[c][4 * kq + 1];
                float w2v = sm.m2.wsm[c][4 * kq + 2], w3v = sm.m2.wsm[c][4 * kq + 3];
                float4 x0 = *(const float4*)&sm.m2.xs[r0 + 0][4 * kq];
                float4 x1 = *(const float4*)&sm.m2.xs[r0 + 1][4 * kq];
                float4 x2 = *(const float4*)&sm.m2.xs[r0 + 2][4 * kq];
                float4 x3 = *(const float4*)&sm.m2.xs[r0 + 3][4 * kq];
                a0 = fmaf(x0.x, w0v, fmaf(x0.y, w1v, fmaf(x0.z, w2v, fmaf(x0.w, w3v, a0))));
                a1 = fmaf(x1.x, w0v, fmaf(x1.y, w1v, fmaf(x1.z, w2v, fmaf(x1.w, w3v, a1))));
                a2 = fmaf(x2.x, w0v, fmaf(x2.y, w1v, fmaf(x2.z, w2v, fmaf(x2.w, w3v, a2))));
                a3 = fmaf(x3.x, w0v, fmaf(x3.y, w1v, fmaf(x3.z, w2v, fmaf(x3.w, w3v, a3))));
            }
            float av[4] = {a0, a1, a2, a3};
            #pragma unroll
            for (int i = 0; i < 4; ++i) {
                int r = r0 + i;
                if (r < nrows) {
                    astore(&a.h2a[(nb + r) * 128 + c], av[i]);
                    sacc += av[i]; qacc += av[i] * av[i];
                }
            }
        }
        sm.m2.rs[t] = sacc; sm.m2.rq[t] = qacc;
        __syncthreads();
        if (t < 128) {
            astore(&a.psum2a[b * 256 + t],       sm.m2.rs[t] + sm.m2.rs[t + 128]);
            astore(&a.psum2a[b * 256 + 128 + t], sm.m2.rq[t] + sm.m2.rq[t + 128]);
        }
    } else {
        int e0 = (b - 32) * 1000;
        for (int e = e0 + t; e < e0 + 1000; e += 256) {
            int s_ = a.ei[e], d_ = a.ei[NE + e];
            int rs_ = aiload(&a.rk_g[s_]), rd_ = aiload(&a.rk_g[d_]);
            bool v = (rs_ < NK1) && (rd_ < NK1);
            aistore(&a.nsrc[e], v ? rs_ : 0);
            aistore(&a.ndst[e], v ? rd_ : 0);
            astore(&a.new_ew[e], v ? a.ea[e] : 0.f);
        }
    }
    gsync(a.bar, 5);

    // ======== P6: lin2b (64 blocks x 8 rows, k-tiled) ========
    {
        const int nb = b * 8;
        if (nb < NK1) {
            const int nrows = (NK1 - nb) < 8 ? (NK1 - nb) : 8;
            if (t < 128) {
                float s = 0.f, q = 0.f;
                for (int i = 0; i < 32; ++i) { s += aload(&a.psum2a[i * 256 + t]); q += aload(&a.psum2a[i * 256 + 128 + t]); }
                float mu = s * (1.f / NK1);
                float var = q * (1.f / NK1) - mu * mu;
                float sv = a.g2a[t] * rsqrtf(var + EPS);
                sm.m3.sc[t] = sv; sm.m3.sh[t] = a.be2a[t] - mu * sv;
            }
            float acc[8];
            float bb = (t < 200) ? a.b2b[t] : 0.f;
            #pragma unroll
            for (int r = 0; r < 8; ++r) acc[r] = bb;
            for (int kt = 0; kt < 4; ++kt) {
                int k0 = kt * 32;
                __syncthreads();
                for (int i = 0; i < 25; ++i) {
                    int e = t + i * 256;
                    int r = e >> 5, k = e & 31;
                    sm.m3.wsm[r][k] = a.w2b[r * 128 + k0 + k];
                }
                {
                    int r = t >> 5, k = t & 31;
                    sm.m3.xs[r][k] = (r < nrows)
                        ? bnr(aload(&a.h2a[(nb + r) * 128 + k0 + k]), sm.m3.sc[k0 + k], sm.m3.sh[k0 + k]) : 0.f;
                }
                __syncthreads();
                if (t < 200) {
                    #pragma unroll
                    for (int kq = 0; kq < 8; ++kq) {
                        float w0v = sm.m3.wsm[t][4 * kq], w1v = sm.m3.wsm[t][4 * kq + 1];
                        float w2v = sm.m3.wsm[t][4 * kq + 2], w3v = sm.m3.wsm[t][4 * kq + 3];
                        #pragma unroll
                        for (int r = 0; r < 8; ++r) {
                            float4 xv = *(const float4*)&sm.m3.xs[r][4 * kq];
                            acc[r] = fmaf(xv.x, w0v, fmaf(xv.y, w1v, fmaf(xv.z, w2v, fmaf(xv.w, w3v, acc[r]))));
                        }
                    }
                }
            }
            if (t < 200) {
                float s = 0.f, q = 0.f;
                #pragma unroll
                for (int r = 0; r < 8; ++r) {
                    if (r < nrows) {
                        astore(&a.h2b[(nb + r) * 200 + t], acc[r]);
                        s += acc[r]; q += acc[r] * acc[r];
                    }
                }
                astore(&a.psum2b[b * 400 + t], s);
                astore(&a.psum2b[b * 400 + 200 + t], q);
            }
        } else if (t < 200) {
            astore(&a.psum2b[b * 400 + t], 0.f);
            astore(&a.psum2b[b * 400 + 200 + t], 0.f);
        }
    }
    gsync(a.bar, 6);

    // ======== P7: score2 (63 blocks x 8 nodes) ========
    if (b < 63) {
        if (t < 200) {
            float s = 0.f, q = 0.f;
            for (int i = 0; i < 64; ++i) { s += aload(&a.psum2b[i * 400 + t]); q += aload(&a.psum2b[i * 400 + 200 + t]); }
            float mu = s * (1.f / NK1);
            float var = q * (1.f / NK1) - mu * mu;
            float sv = a.g2b[t] * rsqrtf(var + EPS);
            sm.bn.sc[t] = sv; sm.bn.sh[t] = a.be2b[t] - mu * sv;
        }
        __syncthreads();
        for (int it = 0; it < 2; ++it) {
            int n = b * 8 + it * 4 + wv;
            if (n < NK1) {
                float dr = 0.f, dt = 0.f;
                #pragma unroll
                for (int j = 0; j < 4; ++j) {
                    int ch = lane + 64 * j;
                    if (ch < 200) {
                        float v = bnr(aload(&a.h2b[n * 200 + ch]), sm.bn.sc[ch], sm.bn.sh[ch]);
                        dr = fmaf(v, a.p2_wrel[ch], dr);
                        dt = fmaf(v, a.p2_wroot[ch], dt);
                    }
                }
                #pragma unroll
                for (int m = 32; m >= 1; m >>= 1) {
                    dr += __shfl_xor(dr, m, 64);
                    dt += __shfl_xor(dt, m, 64);
                }
                if (lane == 0) { astore(&a.t2[n], dr); astore(&a.sc2[n], dt + a.p2_b[0]); }
            }
        }
    }
    gsync(a.bar, 7);

    // ======== P8: scatter2 (16 blocks) ========
    if (b < 16) {
        for (int i = t; i < NK1; i += 256) sm.sct.acc[i] = 0.f;
        __syncthreads();
        for (int e = b * 256 + t; e < NE; e += 16 * 256) {
            float w = aload(&a.new_ew[e]);
            if (w != 0.f) atomicAdd(&sm.sct.acc[aiload(&a.ndst[e])], w * aload(&a.t2[aiload(&a.nsrc[e])]));
        }
        __syncthreads();
        for (int i = t; i < NK1; i += 256) {
            float v = sm.sct.acc[i];
            if (v != 0.f) atomicAdd(&a.sc2[i], v);
        }
    }
    gsync(a.bar, 8);

    // ======== P9: rank2 + select (63 blocks x 8 nodes) ========
    if (b < 63) {
        if (t < 200) {
            float s = 0.f, q = 0.f;
            for (int i = 0; i < 64; ++i) { s += aload(&a.psum2b[i * 400 + t]); q += aload(&a.psum2b[i * 400 + 200 + t]); }
            float mu = s * (1.f / NK1);
            float var = q * (1.f / NK1) - mu * mu;
            float sv = a.g2b[t] * rsqrtf(var + EPS);
            sm.rk.sc[t] = sv; sm.rk.sh[t] = a.be2b[t] - mu * sv;
        }
        for (int i = t; i < NK1; i += 256) sm.rk.ss[i] = aload(&a.sc2[i]);
        __syncthreads();
        for (int it = 0; it < 2; ++it) {
            int n = b * 8 + it * 4 + wv;
            if (n < NK1) {
                float s = sm.rk.ss[n];
                int r = 0;
                for (int m = lane; m < NK1; m += 64) {
                    float smv = sm.rk.ss[m];
                    r += (smv > s) || (smv == s && m < n);
                }
                #pragma unroll
                for (int msk = 32; msk >= 1; msk >>= 1) r += __shfl_xor(r, msk, 64);
                if (r < NK2) {
                    float tn = tanhf(s);
                    #pragma unroll
                    for (int j = 0; j < 4; ++j) {
                        int ch = lane + 64 * j;
                        if (ch < 200)
                            astore(&a.xp2[r * 200 + ch],
                                   bnr(aload(&a.h2b[n * 200 + ch]), sm.rk.sc[ch], sm.rk.sh[ch]) * tn);
                    }
                }
            }
        }
    }
    gsync(a.bar, 9);

    // ======== P10: max-pool + mlp_third + log_softmax (block 0) ========
    if (b == 0) {
        if (t < 200) {
            float m = -1e30f;
            for (int n = 0; n < NK2; ++n) m = fmaxf(m, aload(&a.xp2[n * 200 + t]));
            sm.fin.g[t] = m;
        }
        __syncthreads();
        for (int r = wv; r < 128; r += 4) {
            float p = 0.f;
            #pragma unroll
            for (int j = 0; j < 4; ++j) {
                int ch = lane + 64 * j;
                if (ch < 200) p = fmaf(a.w3a[r * 200 + ch], sm.fin.g[ch], p);
            }
            #pragma unroll
            for (int m = 32; m >= 1; m >>= 1) p += __shfl_xor(p, m, 64);
            if (lane == 0) sm.fin.h3[r] = fmaxf(p + a.b3a[r], 0.f);
        }
        __syncthreads();
        if (t < 128) {
            int ow = t >> 6;
            float p = a.w3b[ow * 128 + lane] * sm.fin.h3[lane]
                    + a.w3b[ow * 128 + 64 + lane] * sm.fin.h3[64 + lane];
            #pragma unroll
            for (int m = 32; m >= 1; m >>= 1) p += __shfl_xor(p, m, 64);
            if (lane == 0) sm.fin.o[ow] = fmaxf(p + a.b3b[ow], 0.f);
        }
        __syncthreads();
        if (t == 0) {
            float m = fmaxf(sm.fin.o[0], sm.fin.o[1]);
            float l = m + logf(expf(sm.fin.o[0] - m) + expf(sm.fin.o[1] - m));
            a.out[0] = sm.fin.o[0] - l;
            a.out[1] = sm.fin.o[1] - l;
        }
    }
}

extern "C" void kernel_launch(void* const* d_in, const int* in_sizes, int n_in,
                              void* d_out, int out_size, void* d_ws, size_t ws_size,
                              hipStream_t stream) {
    float* ws = (float*)d_ws;

    Args a;
    a.x    = (const float*)d_in[0];
    a.ei   = (const int*)d_in[1];
    a.ea   = (const float*)d_in[2];
    a.w0   = (const float*)d_in[3];  a.b0   = (const float*)d_in[4];
    a.g0   = (const float*)d_in[5];  a.be0  = (const float*)d_in[6];
    a.w1   = (const float*)d_in[7];  a.b1   = (const float*)d_in[8];
    a.g1   = (const float*)d_in[9];  a.be1  = (const float*)d_in[10];
    a.w2a  = (const float*)d_in[11]; a.b2a  = (const float*)d_in[12];
    a.g2a  = (const float*)d_in[13]; a.be2a = (const float*)d_in[14];
    a.w2b  = (const float*)d_in[15]; a.b2b  = (const float*)d_in[16];
    a.g2b  = (const float*)d_in[17]; a.be2b = (const float*)d_in[18];
    a.w3a  = (const float*)d_in[19]; a.b3a  = (const float*)d_in[20];
    a.w3b  = (const float*)d_in[21]; a.b3b  = (const float*)d_in[22];
    a.p1_wrel  = (const float*)d_in[23];
    a.p1_wroot = (const float*)d_in[24];
    a.p1_b     = (const float*)d_in[25];
    a.p2_wrel  = (const float*)d_in[26];
    a.p2_wroot = (const float*)d_in[27];
    a.p2_b     = (const float*)d_in[28];

    a.h1     = ws;                      // 64000
    a.psum1  = ws + 64000;              // 4096  (32 x 128)
    a.rk_g   = (int*)(ws + 68096);      // 1000
    a.sc1    = ws + 69096;              // 1000
    a.t1     = ws + 70096;              // 1000
    a.xp1    = ws + 71096;              // 32000
    a.h2a    = ws + 103096;             // 64000
    a.psum2a = ws + 167096;             // 8192  (32 x 256)
    a.h2b    = ws + 175288;             // 100000
    a.psum2b = ws + 275288;             // 25600 (64 x 400)
    a.t2     = ws + 300888;             // 500
    a.sc2    = ws + 301388;             // 500
    a.xp2    = ws + 301888;             // 20000
    a.nsrc   = (int*)(ws + 321888);     // 32000
    a.ndst   = (int*)(ws + 353888);     // 32000
    a.new_ew = ws + 385888;             // 32000
    a.bar    = (unsigned*)(ws + 417888);
    a.out    = (float*)d_out;

    hipMemsetAsync((void*)a.bar, 0, sizeof(unsigned), stream);
    k_mega<<<NBLK, 256, 0, stream>>>(a);
}